// Round 19
// baseline (313.475 us; speedup 1.0000x reference)
//
#include <hip/hip_runtime.h>
#include <stdint.h>

#define N_NODES 50000
#define N_EDGES 800000
#define IN_CH 128
#define HID 256
#define N_GRAPHS 64
#define N_CLASSES 10

#define GEMM_WG ((N_NODES + 127) / 128)       // 391 blocks (full-width tiles)
#define NB ((N_NODES + 127) / 128)            // 391 dst buckets (128 nodes each)
#define EPB 4096                              // edges per bin block
#define CAP 4096                              // slots per bucket (mean 2048, 45 sigma)
#define BIN_B ((N_EDGES + EPB - 1) / EPB)     // 196 bin blocks

#define CVT_X_IDS (N_NODES * IN_CH / 8)       // 800000
#define CVT_W1_IDS (2 * IN_CH * HID)          // 65536
#define CVT_W23_IDS (4 * HID * HID)           // 262144
#define CVT_TOTAL (CVT_X_IDS + CVT_W1_IDS + CVT_W23_IDS)
#define CVT_B ((CVT_TOTAL + 511) / 512)       // 2203
#define PREP_GRID (BIN_B + CVT_B)

typedef unsigned short u16;
typedef __attribute__((ext_vector_type(8))) short short8;
typedef __attribute__((ext_vector_type(4))) float f32x4;

__device__ __forceinline__ float bf2f(uint32_t u) {
    union { uint32_t i; float f; } v; v.i = u << 16; return v.f;
}
__device__ __forceinline__ uint32_t f2bf(float f) {
    union { float f; uint32_t i; } v; v.f = f;
    return (v.i + 0x7FFFu + ((v.i >> 16) & 1u)) >> 16;   // RNE
}

// ===========================================================================
// prep: blocks [0, BIN_B) bin edges into dst-buckets; the rest convert x and
// transpose-convert weights (independent work, one dispatch).
// ===========================================================================
__global__ void __launch_bounds__(512)
prep_kernel(const int* __restrict__ src, const int* __restrict__ dst,
            int* __restrict__ gcnt, uint32_t* __restrict__ tmp,
            const float* __restrict__ x, u16* __restrict__ xb,
            const float* __restrict__ W1r, const float* __restrict__ W1n,
            const float* __restrict__ W2r, const float* __restrict__ W2n,
            const float* __restrict__ W3r, const float* __restrict__ W3n,
            u16* __restrict__ o1r, u16* __restrict__ o1n,
            u16* __restrict__ o2r, u16* __restrict__ o2n,
            u16* __restrict__ o3r, u16* __restrict__ o3n)
{
    if (blockIdx.x < BIN_B) {
        __shared__ int hist[NB];
        __shared__ int base[NB];
        int t = threadIdx.x;
        for (int i = t; i < NB; i += 512) hist[i] = 0;
        __syncthreads();
        const int e0 = blockIdx.x * EPB;
        int b_[8], s_[8], d_[8];
        #pragma unroll
        for (int k = 0; k < 8; ++k) {
            int e = e0 + k * 512 + t;
            if (e < N_EDGES) {
                int d = dst[e];
                b_[k] = d >> 7;
                d_[k] = d & 127;
                s_[k] = src[e];
                atomicAdd(&hist[b_[k]], 1);
            } else b_[k] = -1;
        }
        __syncthreads();
        for (int i = t; i < NB; i += 512) {
            int c = hist[i];
            base[i] = c ? atomicAdd(&gcnt[i], c) : 0;
            hist[i] = 0;
        }
        __syncthreads();
        #pragma unroll
        for (int k = 0; k < 8; ++k) {
            if (b_[k] >= 0) {
                int r = atomicAdd(&hist[b_[k]], 1);
                int pos = base[b_[k]] + r;
                if (pos < CAP)
                    tmp[(size_t)b_[k] * CAP + pos] = ((uint32_t)s_[k] << 7) | (uint32_t)d_[k];
            }
        }
        return;
    }

    int id = (blockIdx.x - BIN_B) * 512 + threadIdx.x;
    if (id < CVT_X_IDS) {
        const float4 a = *reinterpret_cast<const float4*>(x + (size_t)id * 8);
        const float4 b = *reinterpret_cast<const float4*>(x + (size_t)id * 8 + 4);
        uint4 o;
        o.x = f2bf(a.x) | (f2bf(a.y) << 16);
        o.y = f2bf(a.z) | (f2bf(a.w) << 16);
        o.z = f2bf(b.x) | (f2bf(b.y) << 16);
        o.w = f2bf(b.z) | (f2bf(b.w) << 16);
        *reinterpret_cast<uint4*>(xb + (size_t)id * 8) = o;
        return;
    }
    id -= CVT_X_IDS;
    if (id < CVT_W1_IDS) {                             // W1: [128][256]
        int m = id >> 15;
        int r = id & 32767;
        int k = r >> 8, n = r & 255;
        const float* W = m ? W1n : W1r;
        u16* O = m ? o1n : o1r;
        O[n * 128 + k] = (u16)f2bf(W[r]);
        return;
    }
    id -= CVT_W1_IDS;
    if (id < CVT_W23_IDS) {                            // W2/W3: [256][256]
        int m = id >> 16;
        int r = id & 65535;
        int k = r >> 8, n = r & 255;
        const float* W = (m == 0) ? W2r : (m == 1) ? W2n : (m == 2) ? W3r : W3n;
        u16* O = (m == 0) ? o2r : (m == 1) ? o2n : (m == 2) ? o3r : o3n;
        O[n * 256 + k] = (u16)f2bf(W[r]);
    }
}

__global__ void __launch_bounds__(512) bucket_scan(const int* __restrict__ gcnt,
                                                   int* __restrict__ boff,
                                                   int* __restrict__ row_start)
{
    __shared__ int buf[512];
    int t = threadIdx.x;
    int v = (t < NB) ? gcnt[t] : 0;
    buf[t] = v;
    __syncthreads();
    #pragma unroll
    for (int off = 1; off < 512; off <<= 1) {
        int a = (t >= off) ? buf[t - off] : 0;
        __syncthreads();
        buf[t] += a;
        __syncthreads();
    }
    if (t < NB) boff[t] = buf[t] - v;
    if (t == 0) row_start[N_NODES] = N_EDGES;
}

__global__ void __launch_bounds__(256) debin2(const uint32_t* __restrict__ tmp,
                                              const int* __restrict__ gcnt,
                                              const int* __restrict__ boff,
                                              int* __restrict__ row_start,
                                              int* __restrict__ esrc)
{
    __shared__ int h[128];
    __shared__ int pre[128];
    __shared__ int cur[128];
    const int b = blockIdx.x;
    const int n0 = b * 128;
    const int nn = min(128, N_NODES - n0);
    const int t = threadIdx.x;
    const int cnt = min(gcnt[b], CAP);
    const int bb = boff[b];
    const uint32_t* te = tmp + (size_t)b * CAP;

    if (t < 128) h[t] = 0;
    __syncthreads();
    for (int p = t; p < cnt; p += 256)
        atomicAdd(&h[te[p] & 127u], 1);
    __syncthreads();
    if (t < 128) pre[t] = h[t];
    __syncthreads();
    #pragma unroll
    for (int off = 1; off < 128; off <<= 1) {
        int a = (t >= off && t < 128) ? pre[t - off] : 0;
        __syncthreads();
        if (t < 128) pre[t] += a;
        __syncthreads();
    }
    if (t < nn) {
        int rs = bb + pre[t] - h[t];   // exclusive
        row_start[n0 + t] = rs;
        cur[t] = rs;
    }
    __syncthreads();
    for (int p = t; p < cnt; p += 256) {
        uint32_t v = te[p];
        int pos = atomicAdd(&cur[v & 127u], 1);
        esrc[pos] = (int)(v >> 7);
    }
}

// ===========================================================================
// agg[i,:] = sum_{j in in(i)} feat[j,:]  — bf16, fp32 acc, column-phased,
// 8-deep edge unroll (gather is latency-bound at FETCH=118 MB: double the
// in-flight row loads per lane).
// ===========================================================================
template<int D, int NPH>
__global__ void __launch_bounds__(256)
gather_ph(const u16* __restrict__ feat, const int* __restrict__ row_start,
          const int* __restrict__ esrc, u16* __restrict__ agg)
{
    constexpr int CW = D / NPH;        // cols per phase (>= 64)
    constexpr int GS = CW / 8;         // threads per node per phase
    constexpr int NPB = 256 / GS;      // nodes per block
    const int node = blockIdx.x * NPB + threadIdx.x / GS;
    const int lane = threadIdx.x % GS;
    const bool act = node < N_NODES;
    int s = 0, e = 0;
    if (act) { s = row_start[node]; e = row_start[node + 1]; }

    #pragma unroll
    for (int p = 0; p < NPH; ++p) {
        const u16* fp = feat + p * CW + lane * 8;
        float acc[8] = {0.f, 0.f, 0.f, 0.f, 0.f, 0.f, 0.f, 0.f};
        auto add = [&](uint4 v) {
            acc[0] += bf2f(v.x & 0xFFFF); acc[1] += bf2f(v.x >> 16);
            acc[2] += bf2f(v.y & 0xFFFF); acc[3] += bf2f(v.y >> 16);
            acc[4] += bf2f(v.z & 0xFFFF); acc[5] += bf2f(v.z >> 16);
            acc[6] += bf2f(v.w & 0xFFFF); acc[7] += bf2f(v.w >> 16);
        };
        int j = s;
        for (; j + 7 < e; j += 8) {
            int s0 = esrc[j],     s1 = esrc[j + 1], s2 = esrc[j + 2], s3 = esrc[j + 3];
            int s4 = esrc[j + 4], s5 = esrc[j + 5], s6 = esrc[j + 6], s7 = esrc[j + 7];
            uint4 v0 = *reinterpret_cast<const uint4*>(fp + (size_t)s0 * D);
            uint4 v1 = *reinterpret_cast<const uint4*>(fp + (size_t)s1 * D);
            uint4 v2 = *reinterpret_cast<const uint4*>(fp + (size_t)s2 * D);
            uint4 v3 = *reinterpret_cast<const uint4*>(fp + (size_t)s3 * D);
            uint4 v4 = *reinterpret_cast<const uint4*>(fp + (size_t)s4 * D);
            uint4 v5 = *reinterpret_cast<const uint4*>(fp + (size_t)s5 * D);
            uint4 v6 = *reinterpret_cast<const uint4*>(fp + (size_t)s6 * D);
            uint4 v7 = *reinterpret_cast<const uint4*>(fp + (size_t)s7 * D);
            add(v0); add(v1); add(v2); add(v3);
            add(v4); add(v5); add(v6); add(v7);
        }
        for (; j + 3 < e; j += 4) {
            int s0 = esrc[j], s1 = esrc[j + 1], s2 = esrc[j + 2], s3 = esrc[j + 3];
            uint4 v0 = *reinterpret_cast<const uint4*>(fp + (size_t)s0 * D);
            uint4 v1 = *reinterpret_cast<const uint4*>(fp + (size_t)s1 * D);
            uint4 v2 = *reinterpret_cast<const uint4*>(fp + (size_t)s2 * D);
            uint4 v3 = *reinterpret_cast<const uint4*>(fp + (size_t)s3 * D);
            add(v0); add(v1); add(v2); add(v3);
        }
        for (; j < e; ++j) {
            uint4 v0 = *reinterpret_cast<const uint4*>(fp + (size_t)esrc[j] * D);
            add(v0);
        }
        if (act) {
            uint4 o;
            o.x = f2bf(acc[0]) | (f2bf(acc[1]) << 16);
            o.y = f2bf(acc[2]) | (f2bf(acc[3]) << 16);
            o.z = f2bf(acc[4]) | (f2bf(acc[5]) << 16);
            o.w = f2bf(acc[6]) | (f2bf(acc[7]) << 16);
            *reinterpret_cast<uint4*>(agg + (size_t)node * D + p * CW + lane * 8) = o;
        }
        if (p + 1 < NPH) __syncthreads();
    }
}

// ===========================================================================
// C[m,n] = act( A1@W1 + A2@W2 + bias )   — bf16 MFMA, fp32 acc, bf16 out
// FULL-WIDTH tile: BM=128 x BN=256 per 512-thread block (8 waves, 64x64 each)
// ===========================================================================
template<int RELU>
__global__ void __launch_bounds__(512)
mfma_gemm(const u16* __restrict__ A1, const u16* __restrict__ A2,
          const u16* __restrict__ B1t, const u16* __restrict__ B2t,
          const float* __restrict__ bias,
          u16* __restrict__ C,
          int M, int K)
{
    __shared__ __align__(16) u16 As[128][40];
    __shared__ __align__(16) u16 Bs[256][40];

    // bijective XCD chunking (m204)
    const int orig = blockIdx.x;
    const int q = GEMM_WG / 8, r = GEMM_WG % 8;
    const int xcd = orig % 8;
    const int wg = (xcd < r ? xcd * (q + 1) : r * (q + 1) + (xcd - r) * q) + orig / 8;

    const int tid = threadIdx.x;
    const int bm = wg * 128;
    const int w  = tid >> 6;          // 0..7
    const int wm = (w >> 2) * 64;     // 0 or 64
    const int wn = (w & 3) * 64;      // 0,64,128,192
    const int l  = tid & 63;
    const int lr = l & 15;
    const int kb = (l >> 4) * 8;

    f32x4 acc[4][4];
    #pragma unroll
    for (int i = 0; i < 4; ++i)
        #pragma unroll
        for (int j = 0; j < 4; ++j)
            acc[i][j] = (f32x4){0.f, 0.f, 0.f, 0.f};

    const int row_s = tid >> 2;       // 0..127
    const int c8    = (tid & 3) * 8;

    for (int mat = 0; mat < 2; ++mat) {
        const u16* __restrict__ Ag = mat ? A2 : A1;
        const u16* __restrict__ Bg = mat ? B2t : B1t;
        for (int k0 = 0; k0 < K; k0 += 32) {
            {
                uint4 va = make_uint4(0u, 0u, 0u, 0u);
                int gr = bm + row_s;
                if (gr < M)
                    va = *reinterpret_cast<const uint4*>(Ag + (size_t)gr * K + k0 + c8);
                *reinterpret_cast<uint4*>(&As[row_s][c8]) = va;
            }
            #pragma unroll
            for (int it = 0; it < 2; ++it) {
                int row = row_s + it * 128;
                uint4 vb = *reinterpret_cast<const uint4*>(Bg + (size_t)row * K + k0 + c8);
                *reinterpret_cast<uint4*>(&Bs[row][c8]) = vb;
            }
            __syncthreads();
            short8 af[4], bfr[4];
            #pragma unroll
            for (int f = 0; f < 4; ++f) {
                af[f]  = *reinterpret_cast<const short8*>(&As[wm + f * 16 + lr][kb]);
                bfr[f] = *reinterpret_cast<const short8*>(&Bs[wn + f * 16 + lr][kb]);
            }
            #pragma unroll
            for (int fm = 0; fm < 4; ++fm)
                #pragma unroll
                for (int fn = 0; fn < 4; ++fn)
                    acc[fm][fn] = __builtin_amdgcn_mfma_f32_16x16x32_bf16(
                        af[fm], bfr[fn], acc[fm][fn], 0, 0, 0);
            __syncthreads();
        }
    }

    const int r4 = (l >> 4) * 4;
    #pragma unroll
    for (int fm = 0; fm < 4; ++fm) {
        #pragma unroll
        for (int rr = 0; rr < 4; ++rr) {
            int row = bm + wm + fm * 16 + r4 + rr;
            if (row >= M) continue;
            #pragma unroll
            for (int fn = 0; fn < 4; ++fn) {
                int col = wn + fn * 16 + lr;
                float v = acc[fm][fn][rr] + bias[col];
                if (RELU) v = fmaxf(v, 0.f);
                C[(size_t)row * HID + col] = (u16)f2bf(v);
            }
        }
    }
}

// ===========================================================================
// Pooling (batch sorted): inline binary search, two-stage mean + classifier
// ===========================================================================
__device__ __forceinline__ int lower_bound_g(const int* __restrict__ batch, int g)
{
    int lo = 0, hi = N_NODES;
    while (lo < hi) {
        int mid = (lo + hi) >> 1;
        if (batch[mid] < g) lo = mid + 1; else hi = mid;
    }
    return lo;
}

__global__ void pool1_kernel(const u16* __restrict__ h, const int* __restrict__ batch,
                             float* __restrict__ partial)
{
    int g = blockIdx.x >> 3;
    int c = blockIdx.x & 7;
    int t = threadIdx.x;      // 256
    int s = lower_bound_g(batch, g);
    int e = lower_bound_g(batch, g + 1);
    int cnt = e - s;
    int a = s + (int)(((long long)cnt * c) >> 3);
    int b = s + (int)(((long long)cnt * (c + 1)) >> 3);
    float acc = 0.f;
    for (int i = a; i < b; ++i)
        acc += bf2f(h[(size_t)i * HID + t]);
    partial[(size_t)blockIdx.x * HID + t] = acc;
}

__global__ void pool2_final(const float* __restrict__ partial, const int* __restrict__ batch,
                            const float* __restrict__ W_lin, const float* __restrict__ b_lin,
                            float* __restrict__ out)
{
    __shared__ float v[HID];
    int g = blockIdx.x;
    int t = threadIdx.x;
    float acc = 0.f;
    #pragma unroll
    for (int c = 0; c < 8; ++c)
        acc += partial[(size_t)(g * 8 + c) * HID + t];
    float cnt = fmaxf((float)(lower_bound_g(batch, g + 1) - lower_bound_g(batch, g)), 1.f);
    v[t] = acc / cnt;
    __syncthreads();
    if (t < N_CLASSES) {
        float s = b_lin[t];
        for (int k = 0; k < HID; ++k)
            s += v[k] * W_lin[k * N_CLASSES + t];
        out[g * N_CLASSES + t] = s;
    }
}

// ===========================================================================
extern "C" void kernel_launch(void* const* d_in, const int* in_sizes, int n_in,
                              void* d_out, int out_size, void* d_ws, size_t ws_size,
                              hipStream_t stream)
{
    const float* x     = (const float*)d_in[0];
    const int*   ei    = (const int*)d_in[1];
    const int*   batch = (const int*)d_in[2];
    const float* W1r = (const float*)d_in[3];
    const float* W1n = (const float*)d_in[4];
    const float* b1  = (const float*)d_in[5];
    const float* W2r = (const float*)d_in[6];
    const float* W2n = (const float*)d_in[7];
    const float* b2  = (const float*)d_in[8];
    const float* W3r = (const float*)d_in[9];
    const float* W3n = (const float*)d_in[10];
    const float* b3  = (const float*)d_in[11];
    const float* Wl  = (const float*)d_in[12];
    const float* bl  = (const float*)d_in[13];
    float* out = (float*)d_out;

    const int* src = ei;
    const int* dst = ei + N_EDGES;

    char* base = (char*)d_ws;
    size_t off = 0;
    auto alloc = [&](size_t bytes) { char* p = base + off; off += (bytes + 255) & ~(size_t)255; return p; };
    u16* x_bf = (u16*)alloc((size_t)N_NODES * IN_CH * 2);
    u16* hA   = (u16*)alloc((size_t)N_NODES * HID * 2);
    u16* hB   = (u16*)alloc((size_t)N_NODES * HID * 2);
    u16* agg  = (u16*)alloc((size_t)N_NODES * HID * 2);
    u16* wt1r = (u16*)alloc((size_t)HID * IN_CH * 2);
    u16* wt1n = (u16*)alloc((size_t)HID * IN_CH * 2);
    u16* wt2r = (u16*)alloc((size_t)HID * HID * 2);
    u16* wt2n = (u16*)alloc((size_t)HID * HID * 2);
    u16* wt3r = (u16*)alloc((size_t)HID * HID * 2);
    u16* wt3n = (u16*)alloc((size_t)HID * HID * 2);
    float* partial = (float*)alloc((size_t)N_GRAPHS * 8 * HID * 4);
    int* row_start = (int*)alloc((size_t)(N_NODES + 1) * 4);
    int* esrc      = (int*)alloc((size_t)N_EDGES * 4);
    uint32_t* tmp  = (uint32_t*)alloc((size_t)NB * CAP * 4);
    int* gcnt      = (int*)alloc((size_t)NB * 4);
    int* boff      = (int*)alloc((size_t)NB * 4);

    // ---- CSR build + conversions (4 dispatches) ----
    hipMemsetAsync(gcnt, 0, NB * sizeof(int), stream);
    prep_kernel<<<PREP_GRID, 512, 0, stream>>>(src, dst, gcnt, tmp,
                                               x, x_bf, W1r, W1n, W2r, W2n, W3r, W3n,
                                               wt1r, wt1n, wt2r, wt2n, wt3r, wt3n);
    bucket_scan<<<1, 512, 0, stream>>>(gcnt, boff, row_start);
    debin2<<<NB, 256, 0, stream>>>(tmp, gcnt, boff, row_start, esrc);

    // gather grids
    const int G128 = (N_NODES + 31) / 32;
    const int G256 = (N_NODES + 31) / 32;

    // ---- layer 1 (K=128, relu) ----
    gather_ph<IN_CH, 2><<<G128, 256, 0, stream>>>(x_bf, row_start, esrc, agg);
    mfma_gemm<1><<<GEMM_WG, 512, 0, stream>>>(x_bf, agg, wt1r, wt1n, b1, hA, N_NODES, IN_CH);

    // ---- layer 2 (K=256, relu) ----
    gather_ph<HID, 4><<<G256, 256, 0, stream>>>(hA, row_start, esrc, agg);
    mfma_gemm<1><<<GEMM_WG, 512, 0, stream>>>(hA, agg, wt2r, wt2n, b2, hB, N_NODES, HID);

    // ---- layer 3 (K=256, no relu) ----
    gather_ph<HID, 4><<<G256, 256, 0, stream>>>(hB, row_start, esrc, agg);
    mfma_gemm<0><<<GEMM_WG, 512, 0, stream>>>(hB, agg, wt3r, wt3n, b3, hA, N_NODES, HID);

    // ---- pool + classifier (2 dispatches) ----
    pool1_kernel<<<N_GRAPHS * 8, HID, 0, stream>>>(hA, batch, partial);
    pool2_final<<<N_GRAPHS, HID, 0, stream>>>(partial, batch, Wl, bl, out);
}

// Round 20
// 289.704 us; speedup vs baseline: 1.0821x; 1.0821x over previous
//
#include <hip/hip_runtime.h>
#include <stdint.h>

#define N_NODES 50000
#define N_EDGES 800000
#define IN_CH 128
#define HID 256
#define N_GRAPHS 64
#define N_CLASSES 10

#define GEMM_WG ((N_NODES + 127) / 128)       // 391 blocks (full-width tiles)
#define NB ((N_NODES + 127) / 128)            // 391 dst buckets (128 nodes each)
#define EPB 4096                              // edges per bin block
#define CAP 4096                              // slots per bucket (mean 2048, 45 sigma)
#define BIN_B ((N_EDGES + EPB - 1) / EPB)     // 196 bin blocks

#define CVT_X_IDS (N_NODES * IN_CH / 8)       // 800000
#define CVT_W1_IDS (2 * IN_CH * HID)          // 65536
#define CVT_W23_IDS (4 * HID * HID)           // 262144
#define CVT_TOTAL (CVT_X_IDS + CVT_W1_IDS + CVT_W23_IDS)
#define CVT_B ((CVT_TOTAL + 511) / 512)       // 2203
#define PREP_GRID (BIN_B + CVT_B)

typedef unsigned short u16;
typedef __attribute__((ext_vector_type(8))) short short8;
typedef __attribute__((ext_vector_type(4))) float f32x4;

__device__ __forceinline__ float bf2f(uint32_t u) {
    union { uint32_t i; float f; } v; v.i = u << 16; return v.f;
}
__device__ __forceinline__ uint32_t f2bf(float f) {
    union { float f; uint32_t i; } v; v.f = f;
    return (v.i + 0x7FFFu + ((v.i >> 16) & 1u)) >> 16;   // RNE
}

// ===========================================================================
// prep: blocks [0, BIN_B) bin edges into dst-buckets; the rest convert x and
// transpose-convert weights (independent work, one dispatch).
// ===========================================================================
__global__ void __launch_bounds__(512)
prep_kernel(const int* __restrict__ src, const int* __restrict__ dst,
            int* __restrict__ gcnt, uint32_t* __restrict__ tmp,
            const float* __restrict__ x, u16* __restrict__ xb,
            const float* __restrict__ W1r, const float* __restrict__ W1n,
            const float* __restrict__ W2r, const float* __restrict__ W2n,
            const float* __restrict__ W3r, const float* __restrict__ W3n,
            u16* __restrict__ o1r, u16* __restrict__ o1n,
            u16* __restrict__ o2r, u16* __restrict__ o2n,
            u16* __restrict__ o3r, u16* __restrict__ o3n)
{
    if (blockIdx.x < BIN_B) {
        __shared__ int hist[NB];
        __shared__ int base[NB];
        int t = threadIdx.x;
        for (int i = t; i < NB; i += 512) hist[i] = 0;
        __syncthreads();
        const int e0 = blockIdx.x * EPB;
        int b_[8], s_[8], d_[8];
        #pragma unroll
        for (int k = 0; k < 8; ++k) {
            int e = e0 + k * 512 + t;
            if (e < N_EDGES) {
                int d = dst[e];
                b_[k] = d >> 7;
                d_[k] = d & 127;
                s_[k] = src[e];
                atomicAdd(&hist[b_[k]], 1);
            } else b_[k] = -1;
        }
        __syncthreads();
        for (int i = t; i < NB; i += 512) {
            int c = hist[i];
            base[i] = c ? atomicAdd(&gcnt[i], c) : 0;
            hist[i] = 0;
        }
        __syncthreads();
        #pragma unroll
        for (int k = 0; k < 8; ++k) {
            if (b_[k] >= 0) {
                int r = atomicAdd(&hist[b_[k]], 1);
                int pos = base[b_[k]] + r;
                if (pos < CAP)
                    tmp[(size_t)b_[k] * CAP + pos] = ((uint32_t)s_[k] << 7) | (uint32_t)d_[k];
            }
        }
        return;
    }

    int id = (blockIdx.x - BIN_B) * 512 + threadIdx.x;
    if (id < CVT_X_IDS) {
        const float4 a = *reinterpret_cast<const float4*>(x + (size_t)id * 8);
        const float4 b = *reinterpret_cast<const float4*>(x + (size_t)id * 8 + 4);
        uint4 o;
        o.x = f2bf(a.x) | (f2bf(a.y) << 16);
        o.y = f2bf(a.z) | (f2bf(a.w) << 16);
        o.z = f2bf(b.x) | (f2bf(b.y) << 16);
        o.w = f2bf(b.z) | (f2bf(b.w) << 16);
        *reinterpret_cast<uint4*>(xb + (size_t)id * 8) = o;
        return;
    }
    id -= CVT_X_IDS;
    if (id < CVT_W1_IDS) {                             // W1: [128][256]
        int m = id >> 15;
        int r = id & 32767;
        int k = r >> 8, n = r & 255;
        const float* W = m ? W1n : W1r;
        u16* O = m ? o1n : o1r;
        O[n * 128 + k] = (u16)f2bf(W[r]);
        return;
    }
    id -= CVT_W1_IDS;
    if (id < CVT_W23_IDS) {                            // W2/W3: [256][256]
        int m = id >> 16;
        int r = id & 65535;
        int k = r >> 8, n = r & 255;
        const float* W = (m == 0) ? W2r : (m == 1) ? W2n : (m == 2) ? W3r : W3n;
        u16* O = (m == 0) ? o2r : (m == 1) ? o2n : (m == 2) ? o3r : o3n;
        O[n * 256 + k] = (u16)f2bf(W[r]);
    }
}

__global__ void __launch_bounds__(512) bucket_scan(const int* __restrict__ gcnt,
                                                   int* __restrict__ boff,
                                                   int* __restrict__ row_start)
{
    __shared__ int buf[512];
    int t = threadIdx.x;
    int v = (t < NB) ? gcnt[t] : 0;
    buf[t] = v;
    __syncthreads();
    #pragma unroll
    for (int off = 1; off < 512; off <<= 1) {
        int a = (t >= off) ? buf[t - off] : 0;
        __syncthreads();
        buf[t] += a;
        __syncthreads();
    }
    if (t < NB) boff[t] = buf[t] - v;
    if (t == 0) row_start[N_NODES] = N_EDGES;
}

__global__ void __launch_bounds__(256) debin2(const uint32_t* __restrict__ tmp,
                                              const int* __restrict__ gcnt,
                                              const int* __restrict__ boff,
                                              int* __restrict__ row_start,
                                              int* __restrict__ esrc)
{
    __shared__ int h[128];
    __shared__ int pre[128];
    __shared__ int cur[128];
    const int b = blockIdx.x;
    const int n0 = b * 128;
    const int nn = min(128, N_NODES - n0);
    const int t = threadIdx.x;
    const int cnt = min(gcnt[b], CAP);
    const int bb = boff[b];
    const uint32_t* te = tmp + (size_t)b * CAP;

    if (t < 128) h[t] = 0;
    __syncthreads();
    for (int p = t; p < cnt; p += 256)
        atomicAdd(&h[te[p] & 127u], 1);
    __syncthreads();
    if (t < 128) pre[t] = h[t];
    __syncthreads();
    #pragma unroll
    for (int off = 1; off < 128; off <<= 1) {
        int a = (t >= off && t < 128) ? pre[t - off] : 0;
        __syncthreads();
        if (t < 128) pre[t] += a;
        __syncthreads();
    }
    if (t < nn) {
        int rs = bb + pre[t] - h[t];   // exclusive
        row_start[n0 + t] = rs;
        cur[t] = rs;
    }
    __syncthreads();
    for (int p = t; p < cnt; p += 256) {
        uint32_t v = te[p];
        int pos = atomicAdd(&cur[v & 127u], 1);
        esrc[pos] = (int)(v >> 7);
    }
}

// ===========================================================================
// agg[i,:] = sum_{j in in(i)} feat[j,:]  — bf16, fp32 acc, column-phased,
// 4-deep edge unroll (proven R17 config: 28 VGPR, ~49% occupancy).
// ===========================================================================
template<int D, int NPH>
__global__ void __launch_bounds__(256)
gather_ph(const u16* __restrict__ feat, const int* __restrict__ row_start,
          const int* __restrict__ esrc, u16* __restrict__ agg)
{
    constexpr int CW = D / NPH;        // cols per phase (>= 64)
    constexpr int GS = CW / 8;         // threads per node per phase
    constexpr int NPB = 256 / GS;      // nodes per block
    const int node = blockIdx.x * NPB + threadIdx.x / GS;
    const int lane = threadIdx.x % GS;
    const bool act = node < N_NODES;
    int s = 0, e = 0;
    if (act) { s = row_start[node]; e = row_start[node + 1]; }

    #pragma unroll
    for (int p = 0; p < NPH; ++p) {
        const u16* fp = feat + p * CW + lane * 8;
        float acc[8] = {0.f, 0.f, 0.f, 0.f, 0.f, 0.f, 0.f, 0.f};
        auto add = [&](uint4 v) {
            acc[0] += bf2f(v.x & 0xFFFF); acc[1] += bf2f(v.x >> 16);
            acc[2] += bf2f(v.y & 0xFFFF); acc[3] += bf2f(v.y >> 16);
            acc[4] += bf2f(v.z & 0xFFFF); acc[5] += bf2f(v.z >> 16);
            acc[6] += bf2f(v.w & 0xFFFF); acc[7] += bf2f(v.w >> 16);
        };
        int j = s;
        for (; j + 3 < e; j += 4) {
            int s0 = esrc[j], s1 = esrc[j + 1], s2 = esrc[j + 2], s3 = esrc[j + 3];
            uint4 v0 = *reinterpret_cast<const uint4*>(fp + (size_t)s0 * D);
            uint4 v1 = *reinterpret_cast<const uint4*>(fp + (size_t)s1 * D);
            uint4 v2 = *reinterpret_cast<const uint4*>(fp + (size_t)s2 * D);
            uint4 v3 = *reinterpret_cast<const uint4*>(fp + (size_t)s3 * D);
            add(v0); add(v1); add(v2); add(v3);
        }
        for (; j < e; ++j) {
            uint4 v0 = *reinterpret_cast<const uint4*>(fp + (size_t)esrc[j] * D);
            add(v0);
        }
        if (act) {
            uint4 o;
            o.x = f2bf(acc[0]) | (f2bf(acc[1]) << 16);
            o.y = f2bf(acc[2]) | (f2bf(acc[3]) << 16);
            o.z = f2bf(acc[4]) | (f2bf(acc[5]) << 16);
            o.w = f2bf(acc[6]) | (f2bf(acc[7]) << 16);
            *reinterpret_cast<uint4*>(agg + (size_t)node * D + p * CW + lane * 8) = o;
        }
        if (p + 1 < NPH) __syncthreads();
    }
}

// ===========================================================================
// C[m,n] = act( A1@W1 + A2@W2 + bias )   — bf16 MFMA, fp32 acc, bf16 out
// FULL-WIDTH tile: BM=128 x BN=256 per 512-thread block (8 waves, 64x64 each)
// ===========================================================================
template<int RELU>
__global__ void __launch_bounds__(512)
mfma_gemm(const u16* __restrict__ A1, const u16* __restrict__ A2,
          const u16* __restrict__ B1t, const u16* __restrict__ B2t,
          const float* __restrict__ bias,
          u16* __restrict__ C,
          int M, int K)
{
    __shared__ __align__(16) u16 As[128][40];
    __shared__ __align__(16) u16 Bs[256][40];

    // bijective XCD chunking (m204)
    const int orig = blockIdx.x;
    const int q = GEMM_WG / 8, r = GEMM_WG % 8;
    const int xcd = orig % 8;
    const int wg = (xcd < r ? xcd * (q + 1) : r * (q + 1) + (xcd - r) * q) + orig / 8;

    const int tid = threadIdx.x;
    const int bm = wg * 128;
    const int w  = tid >> 6;          // 0..7
    const int wm = (w >> 2) * 64;     // 0 or 64
    const int wn = (w & 3) * 64;      // 0,64,128,192
    const int l  = tid & 63;
    const int lr = l & 15;
    const int kb = (l >> 4) * 8;

    f32x4 acc[4][4];
    #pragma unroll
    for (int i = 0; i < 4; ++i)
        #pragma unroll
        for (int j = 0; j < 4; ++j)
            acc[i][j] = (f32x4){0.f, 0.f, 0.f, 0.f};

    const int row_s = tid >> 2;       // 0..127
    const int c8    = (tid & 3) * 8;

    for (int mat = 0; mat < 2; ++mat) {
        const u16* __restrict__ Ag = mat ? A2 : A1;
        const u16* __restrict__ Bg = mat ? B2t : B1t;
        for (int k0 = 0; k0 < K; k0 += 32) {
            {
                uint4 va = make_uint4(0u, 0u, 0u, 0u);
                int gr = bm + row_s;
                if (gr < M)
                    va = *reinterpret_cast<const uint4*>(Ag + (size_t)gr * K + k0 + c8);
                *reinterpret_cast<uint4*>(&As[row_s][c8]) = va;
            }
            #pragma unroll
            for (int it = 0; it < 2; ++it) {
                int row = row_s + it * 128;
                uint4 vb = *reinterpret_cast<const uint4*>(Bg + (size_t)row * K + k0 + c8);
                *reinterpret_cast<uint4*>(&Bs[row][c8]) = vb;
            }
            __syncthreads();
            short8 af[4], bfr[4];
            #pragma unroll
            for (int f = 0; f < 4; ++f) {
                af[f]  = *reinterpret_cast<const short8*>(&As[wm + f * 16 + lr][kb]);
                bfr[f] = *reinterpret_cast<const short8*>(&Bs[wn + f * 16 + lr][kb]);
            }
            #pragma unroll
            for (int fm = 0; fm < 4; ++fm)
                #pragma unroll
                for (int fn = 0; fn < 4; ++fn)
                    acc[fm][fn] = __builtin_amdgcn_mfma_f32_16x16x32_bf16(
                        af[fm], bfr[fn], acc[fm][fn], 0, 0, 0);
            __syncthreads();
        }
    }

    const int r4 = (l >> 4) * 4;
    #pragma unroll
    for (int fm = 0; fm < 4; ++fm) {
        #pragma unroll
        for (int rr = 0; rr < 4; ++rr) {
            int row = bm + wm + fm * 16 + r4 + rr;
            if (row >= M) continue;
            #pragma unroll
            for (int fn = 0; fn < 4; ++fn) {
                int col = wn + fn * 16 + lr;
                float v = acc[fm][fn][rr] + bias[col];
                if (RELU) v = fmaxf(v, 0.f);
                C[(size_t)row * HID + col] = (u16)f2bf(v);
            }
        }
    }
}

// ===========================================================================
// Pooling (batch sorted): inline binary search, two-stage mean + classifier
// ===========================================================================
__device__ __forceinline__ int lower_bound_g(const int* __restrict__ batch, int g)
{
    int lo = 0, hi = N_NODES;
    while (lo < hi) {
        int mid = (lo + hi) >> 1;
        if (batch[mid] < g) lo = mid + 1; else hi = mid;
    }
    return lo;
}

__global__ void pool1_kernel(const u16* __restrict__ h, const int* __restrict__ batch,
                             float* __restrict__ partial)
{
    int g = blockIdx.x >> 3;
    int c = blockIdx.x & 7;
    int t = threadIdx.x;      // 256
    int s = lower_bound_g(batch, g);
    int e = lower_bound_g(batch, g + 1);
    int cnt = e - s;
    int a = s + (int)(((long long)cnt * c) >> 3);
    int b = s + (int)(((long long)cnt * (c + 1)) >> 3);
    float acc = 0.f;
    for (int i = a; i < b; ++i)
        acc += bf2f(h[(size_t)i * HID + t]);
    partial[(size_t)blockIdx.x * HID + t] = acc;
}

__global__ void pool2_final(const float* __restrict__ partial, const int* __restrict__ batch,
                            const float* __restrict__ W_lin, const float* __restrict__ b_lin,
                            float* __restrict__ out)
{
    __shared__ float v[HID];
    int g = blockIdx.x;
    int t = threadIdx.x;
    float acc = 0.f;
    #pragma unroll
    for (int c = 0; c < 8; ++c)
        acc += partial[(size_t)(g * 8 + c) * HID + t];
    float cnt = fmaxf((float)(lower_bound_g(batch, g + 1) - lower_bound_g(batch, g)), 1.f);
    v[t] = acc / cnt;
    __syncthreads();
    if (t < N_CLASSES) {
        float s = b_lin[t];
        for (int k = 0; k < HID; ++k)
            s += v[k] * W_lin[k * N_CLASSES + t];
        out[g * N_CLASSES + t] = s;
    }
}

// ===========================================================================
extern "C" void kernel_launch(void* const* d_in, const int* in_sizes, int n_in,
                              void* d_out, int out_size, void* d_ws, size_t ws_size,
                              hipStream_t stream)
{
    const float* x     = (const float*)d_in[0];
    const int*   ei    = (const int*)d_in[1];
    const int*   batch = (const int*)d_in[2];
    const float* W1r = (const float*)d_in[3];
    const float* W1n = (const float*)d_in[4];
    const float* b1  = (const float*)d_in[5];
    const float* W2r = (const float*)d_in[6];
    const float* W2n = (const float*)d_in[7];
    const float* b2  = (const float*)d_in[8];
    const float* W3r = (const float*)d_in[9];
    const float* W3n = (const float*)d_in[10];
    const float* b3  = (const float*)d_in[11];
    const float* Wl  = (const float*)d_in[12];
    const float* bl  = (const float*)d_in[13];
    float* out = (float*)d_out;

    const int* src = ei;
    const int* dst = ei + N_EDGES;

    char* base = (char*)d_ws;
    size_t off = 0;
    auto alloc = [&](size_t bytes) { char* p = base + off; off += (bytes + 255) & ~(size_t)255; return p; };
    u16* x_bf = (u16*)alloc((size_t)N_NODES * IN_CH * 2);
    u16* hA   = (u16*)alloc((size_t)N_NODES * HID * 2);
    u16* hB   = (u16*)alloc((size_t)N_NODES * HID * 2);
    u16* agg  = (u16*)alloc((size_t)N_NODES * HID * 2);
    u16* wt1r = (u16*)alloc((size_t)HID * IN_CH * 2);
    u16* wt1n = (u16*)alloc((size_t)HID * IN_CH * 2);
    u16* wt2r = (u16*)alloc((size_t)HID * HID * 2);
    u16* wt2n = (u16*)alloc((size_t)HID * HID * 2);
    u16* wt3r = (u16*)alloc((size_t)HID * HID * 2);
    u16* wt3n = (u16*)alloc((size_t)HID * HID * 2);
    float* partial = (float*)alloc((size_t)N_GRAPHS * 8 * HID * 4);
    int* row_start = (int*)alloc((size_t)(N_NODES + 1) * 4);
    int* esrc      = (int*)alloc((size_t)N_EDGES * 4);
    uint32_t* tmp  = (uint32_t*)alloc((size_t)NB * CAP * 4);
    int* gcnt      = (int*)alloc((size_t)NB * 4);
    int* boff      = (int*)alloc((size_t)NB * 4);

    // ---- CSR build + conversions (4 dispatches) ----
    hipMemsetAsync(gcnt, 0, NB * sizeof(int), stream);
    prep_kernel<<<PREP_GRID, 512, 0, stream>>>(src, dst, gcnt, tmp,
                                               x, x_bf, W1r, W1n, W2r, W2n, W3r, W3n,
                                               wt1r, wt1n, wt2r, wt2n, wt3r, wt3n);
    bucket_scan<<<1, 512, 0, stream>>>(gcnt, boff, row_start);
    debin2<<<NB, 256, 0, stream>>>(tmp, gcnt, boff, row_start, esrc);

    // gather grids
    const int G128 = (N_NODES + 31) / 32;
    const int G256 = (N_NODES + 31) / 32;

    // ---- layer 1 (K=128, relu) ----
    gather_ph<IN_CH, 2><<<G128, 256, 0, stream>>>(x_bf, row_start, esrc, agg);
    mfma_gemm<1><<<GEMM_WG, 512, 0, stream>>>(x_bf, agg, wt1r, wt1n, b1, hA, N_NODES, IN_CH);

    // ---- layer 2 (K=256, relu) ----
    gather_ph<HID, 4><<<G256, 256, 0, stream>>>(hA, row_start, esrc, agg);
    mfma_gemm<1><<<GEMM_WG, 512, 0, stream>>>(hA, agg, wt2r, wt2n, b2, hB, N_NODES, HID);

    // ---- layer 3 (K=256, no relu) ----
    gather_ph<HID, 4><<<G256, 256, 0, stream>>>(hB, row_start, esrc, agg);
    mfma_gemm<0><<<GEMM_WG, 512, 0, stream>>>(hB, agg, wt3r, wt3n, b3, hA, N_NODES, HID);

    // ---- pool + classifier (2 dispatches) ----
    pool1_kernel<<<N_GRAPHS * 8, HID, 0, stream>>>(hA, batch, partial);
    pool2_final<<<N_GRAPHS, HID, 0, stream>>>(partial, batch, Wl, bl, out);
}